// Round 1
// baseline (657.362 us; speedup 1.0000x reference)
//
#include <hip/hip_runtime.h>
#include <stdint.h>

#define NH 16
#define HD 64
#define DM 1024
#define BB 2
#define LL 2048

typedef __bf16 bf16x8 __attribute__((ext_vector_type(8)));
typedef float f32x4 __attribute__((ext_vector_type(4)));
typedef unsigned short u16x8 __attribute__((ext_vector_type(8)));

__device__ __forceinline__ uint16_t f2bf(float f) {
  union { float f; uint32_t u; } x{f};
  uint32_t r = (x.u + 0x7fff + ((x.u >> 16) & 1)) >> 16;
  return (uint16_t)r;
}

__device__ __forceinline__ void gload_lds16(const void* g, void* l) {
  __builtin_amdgcn_global_load_lds(
      (const __attribute__((address_space(1))) unsigned int*)g,
      (__attribute__((address_space(3))) unsigned int*)l, 16, 0, 0);
}

// ---------------- fp32 -> bf16 cast (same layout)
__global__ __launch_bounds__(256) void cvt_bf16(
    const float* __restrict__ x, uint16_t* __restrict__ y, int n4) {
  int i = blockIdx.x * 256 + threadIdx.x;
  if (i >= n4) return;
  float4 v = ((const float4*)x)[i];
  ushort4 o;
  o.x = f2bf(v.x); o.y = f2bf(v.y); o.z = f2bf(v.z); o.w = f2bf(v.w);
  ((ushort4*)y)[i] = o;
}

// ---------------- fp32 [K,N] -> bf16 [N,K] transpose-cast
__global__ __launch_bounds__(256) void transpose_cvt(
    const float* __restrict__ W, uint16_t* __restrict__ WT, int K, int N) {
  __shared__ float t[32][33];
  int bk = blockIdx.y * 32, bn = blockIdx.x * 32;
  int c = threadIdx.x & 31, r0 = threadIdx.x >> 5;
#pragma unroll
  for (int p = 0; p < 4; ++p) {
    int r = r0 + p * 8;
    t[r][c] = W[(size_t)(bk + r) * N + bn + c];
  }
  __syncthreads();
#pragma unroll
  for (int p = 0; p < 4; ++p) {
    int r = r0 + p * 8;
    WT[(size_t)(bn + r) * K + bk + c] = f2bf(t[c][r]);
  }
}

// ---------------- bf16 MFMA GEMM: C[M,N] = A @ BT^T + bias
// Swapped-operand mfma(bfr, af): lane&15 = C-row, (lane>>4)*4+reg = C-col
// -> vectorized epilogue (float4 / ushort4 per lane).
// OBF=1: C is bf16 (uint16_t*), OBF=0: C is fp32 (float*).
template <int OBF>
__global__ __launch_bounds__(256) void gemm_bt(
    const uint16_t* __restrict__ A, const uint16_t* __restrict__ BT,
    const float* __restrict__ bias, void* __restrict__ Cout,
    int M, int N, int K) {
  __shared__ uint16_t As[128 * 32];
  __shared__ uint16_t Bs[128 * 32];
  const int tid = threadIdx.x;
  const int bm = blockIdx.y * 128, bn = blockIdx.x * 128;
  const int lane = tid & 63, wave = tid >> 6;
  const int wr = wave >> 1, wc = wave & 1;
  f32x4 acc[4][4] = {};

  for (int k0 = 0; k0 < K; k0 += 32) {
#pragma unroll
    for (int c = 0; c < 2; ++c) {
      int e = c * 2048 + tid * 8;
      int r = e >> 5, col = e & 31;
      gload_lds16(A + (size_t)(bm + r) * K + k0 + col, (char*)As + (size_t)e * 2);
      gload_lds16(BT + (size_t)(bn + r) * K + k0 + col, (char*)Bs + (size_t)e * 2);
    }
    __syncthreads();

    const int kseg = (lane >> 4) * 8;
    bf16x8 af[4], bfr[4];
#pragma unroll
    for (int i = 0; i < 4; ++i)
      af[i] = *(const bf16x8*)&As[(wr * 64 + i * 16 + (lane & 15)) * 32 + kseg];
#pragma unroll
    for (int j = 0; j < 4; ++j)
      bfr[j] = *(const bf16x8*)&Bs[(wc * 64 + j * 16 + (lane & 15)) * 32 + kseg];
#pragma unroll
    for (int i = 0; i < 4; ++i)
#pragma unroll
      for (int j = 0; j < 4; ++j)
        acc[i][j] = __builtin_amdgcn_mfma_f32_16x16x32_bf16(bfr[j], af[i], acc[i][j], 0, 0, 0);
    __syncthreads();
  }

#pragma unroll
  for (int i = 0; i < 4; ++i) {
#pragma unroll
    for (int j = 0; j < 4; ++j) {
      int row = bm + wr * 64 + i * 16 + (lane & 15);
      int col = bn + wc * 64 + j * 16 + (lane >> 4) * 4;
      f32x4 bv = *(const f32x4*)&bias[col];
      f32x4 v = acc[i][j] + bv;
      if (OBF) {
        ushort4 o;
        o.x = f2bf(v[0]); o.y = f2bf(v[1]); o.z = f2bf(v[2]); o.w = f2bf(v[3]);
        *(ushort4*)&((uint16_t*)Cout)[(size_t)row * N + col] = o;
      } else {
        *(f32x4*)&((float*)Cout)[(size_t)row * N + col] = v;
      }
    }
  }
}

// ---------------- MFMA sliding-window attention (bf16 qkv input)
// Per block: 32 q-rows, 160-key window (kbase 32-aligned). 4 waves.
// S = Q K^T via mfma 16x16x32 (bf16), softmax fp32, P -> LDS bf16,
// O = P V via mfma with V gathered from global as B-fragment.
#define QT 32
#define KT 160
#define KS 72    // Ks/Qs row stride (bf16): 144 B, 16B-aligned
#define PS 168   // Sf/Psb row stride: Sf 672 B, Psb 336 B

__global__ __launch_bounds__(256, 4) void attn_sw(
    const uint16_t* __restrict__ qkv,  // [B*L, 3*DM] bf16
    float* __restrict__ attnw,         // [B,NH,L,L] - fully written here
    uint16_t* __restrict__ ctxb,       // [B*L, DM] bf16
    const int* __restrict__ wsz_p) {
  __shared__ __align__(16) char smemU[KT * KS * 2];     // Ksb (bf16) / Sf (f32)
  __shared__ __align__(16) uint16_t Qs[QT * KS];
  __shared__ __align__(16) uint16_t Psb[QT * PS];
  uint16_t* Ksb = (uint16_t*)smemU;   // [160][72] bf16
  float* Sf = (float*)smemU;          // [32][168] f32 (after K no longer needed)

  const int wsz = *wsz_p;  // 128
  const int tid = threadIdx.x;
  const int lane = tid & 63, wave = tid >> 6;
  const int ntile = LL / QT;
  const int qt = blockIdx.x % ntile;
  const int h = (blockIdx.x / ntile) % NH;
  const int b = blockIdx.x / (ntile * NH);
  const int q0 = qt * QT;
  const int kmin = max(0, q0 - (wsz - 1));
  const int kbase = kmin & ~31;  // 32-aligned; window rows always in-tensor

  // ---- P0: stage Q (32x64) and K (160x64), pure 16B bf16 copies
  {
    int r = tid >> 3, c = (tid & 7) * 8;
    *(u16x8*)&Qs[r * KS + c] =
        *(const u16x8*)(qkv + (size_t)(b * LL + q0 + r) * (3 * DM) + h * HD + c);
  }
#pragma unroll
  for (int p = 0; p < 5; ++p) {  // 160 rows * 8 chunks = 1280 = 5*256
    int u = tid + p * 256;
    int r = u >> 3, c = (u & 7) * 8;
    *(u16x8*)&Ksb[r * KS + c] =
        *(const u16x8*)(qkv + (size_t)(b * LL + kbase + r) * (3 * DM) + DM + h * HD + c);
  }
  __syncthreads();

  // ---- P1a: S-fragments in registers. wave w: m-tile (w&1), n-tiles [(w>>1)*5 ..+5)
  const int mt = wave & 1, ntb = (wave >> 1) * 5;
  f32x4 sfrag[5];
  {
    const int kseg = (lane >> 4) * 8;
    bf16x8 aq0 = *(const bf16x8*)&Qs[(mt * 16 + (lane & 15)) * KS + kseg];
    bf16x8 aq1 = *(const bf16x8*)&Qs[(mt * 16 + (lane & 15)) * KS + 32 + kseg];
#pragma unroll
    for (int t = 0; t < 5; ++t) {
      int nt = ntb + t;
      bf16x8 bk0 = *(const bf16x8*)&Ksb[(nt * 16 + (lane & 15)) * KS + kseg];
      bf16x8 bk1 = *(const bf16x8*)&Ksb[(nt * 16 + (lane & 15)) * KS + 32 + kseg];
      f32x4 c = {0.f, 0.f, 0.f, 0.f};
      c = __builtin_amdgcn_mfma_f32_16x16x32_bf16(aq0, bk0, c, 0, 0, 0);
      c = __builtin_amdgcn_mfma_f32_16x16x32_bf16(aq1, bk1, c, 0, 0, 0);
      sfrag[t] = c;
    }
  }
  __syncthreads();  // Ksb reads done; Sf may now overwrite the union

  // ---- P1b: spill S-fragments to Sf (fp32)
#pragma unroll
  for (int t = 0; t < 5; ++t) {
    int nt = ntb + t;
#pragma unroll
    for (int r = 0; r < 4; ++r)
      Sf[(mt * 16 + (lane >> 4) * 4 + r) * PS + nt * 16 + (lane & 15)] = sfrag[t][r];
  }
  __syncthreads();

  // ---- P2: softmax (octet per q-row), probs -> Sf (f32) and Psb (bf16)
  {
    const int qi = tid >> 3;
    const int kg = tid & 7;
    const int q = q0 + qi;
    float s[20];
#pragma unroll
    for (int j = 0; j < 20; ++j) s[j] = Sf[qi * PS + kg + 8 * j];
    float m = -1e30f;
#pragma unroll
    for (int j = 0; j < 20; ++j) {
      int gk = kbase + kg + 8 * j;
      bool valid = (gk <= q) && (gk > q - wsz);
      s[j] = valid ? s[j] * 0.125f : -1e30f;
      m = fmaxf(m, s[j]);
    }
#pragma unroll
    for (int off = 1; off < 8; off <<= 1)
      m = fmaxf(m, __shfl_xor(m, off, 64));
    float l = 0.f;
#pragma unroll
    for (int j = 0; j < 20; ++j) {
      float e = (s[j] > -1e29f) ? __expf(s[j] - m) : 0.f;
      s[j] = e;
      l += e;
    }
#pragma unroll
    for (int off = 1; off < 8; off <<= 1)
      l += __shfl_xor(l, off, 64);
    float inv = 1.f / l;
#pragma unroll
    for (int j = 0; j < 20; ++j) {
      float p = s[j] * inv;
      Sf[qi * PS + kg + 8 * j] = p;
      Psb[qi * PS + kg + 8 * j] = f2bf(p);
    }
  }
  __syncthreads();

  // ---- P3: full attnw rows (zeros + band) from Sf, nt float4 stores.
  // Issued before PV so the HBM write stream overlaps the MFMA work.
  {
#pragma unroll
    for (int it = 0; it < 16; ++it) {
      int r = it * 2 + (tid >> 7);
      size_t rowoff = ((size_t)((b * NH + h) * LL + q0 + r)) * LL;
      int cb = (tid & 127) * 4;
#pragma unroll
      for (int jj = 0; jj < 4; ++jj) {
        int c4 = cb + jj * 512;
        f32x4 v = {0.f, 0.f, 0.f, 0.f};
        int pc = c4 - kbase;
        if (pc >= 0 && pc < KT)
          v = *(const f32x4*)&Sf[r * PS + pc];
        __builtin_nontemporal_store(v, (f32x4*)&attnw[rowoff + c4]);
      }
    }
  }

  // ---- P4: O = P V via MFMA. wave w: n-tile (d-cols) = w; both m-tiles.
  {
    const int nt = wave;           // d block: nt*16 + (lane&15)
    const int kseg = (lane >> 4) * 8;
    f32x4 ofrag[2] = {};
#pragma unroll
    for (int ks = 0; ks < 5; ++ks) {
      // B-fragment: V^T[d][key], gathered from global (bf16, 2B loads)
      const uint16_t* vs = qkv + (size_t)(b * LL + kbase + ks * 32 + kseg) * (3 * DM) +
                           2 * DM + h * HD + nt * 16 + (lane & 15);
      uint16_t vb[8];
#pragma unroll
      for (int j = 0; j < 8; ++j) vb[j] = vs[(size_t)j * (3 * DM)];
      bf16x8 bv = *(const bf16x8*)vb;
#pragma unroll
      for (int m = 0; m < 2; ++m) {
        bf16x8 ap = *(const bf16x8*)&Psb[(m * 16 + (lane & 15)) * PS + ks * 32 + kseg];
        ofrag[m] = __builtin_amdgcn_mfma_f32_16x16x32_bf16(ap, bv, ofrag[m], 0, 0, 0);
      }
    }
#pragma unroll
    for (int m = 0; m < 2; ++m)
#pragma unroll
      for (int r = 0; r < 4; ++r) {
        int q = q0 + m * 16 + (lane >> 4) * 4 + r;
        ctxb[(size_t)(b * LL + q) * DM + h * HD + nt * 16 + (lane & 15)] = f2bf(ofrag[m][r]);
      }
  }
}

extern "C" void kernel_launch(void* const* d_in, const int* in_sizes, int n_in,
                              void* d_out, int out_size, void* d_ws, size_t ws_size,
                              hipStream_t stream) {
  const float* hs    = (const float*)d_in[0];
  const float* Wqkv  = (const float*)d_in[1];
  const float* bqkv  = (const float*)d_in[2];
  const float* Wproj = (const float*)d_in[3];
  const float* bproj = (const float*)d_in[4];
  const int*   wszp  = (const int*)d_in[5];

  float* out   = (float*)d_out;
  float* attnw = (float*)d_out + (size_t)BB * LL * DM;

  char* wsb = (char*)d_ws;
  uint16_t* qkv    = (uint16_t*)wsb;                           // 25165824 B (bf16 now)
  uint16_t* hsctxb = (uint16_t*)(wsb + 25165824);              //  8388608 B
  uint16_t* WqkvT  = (uint16_t*)(wsb + 25165824 + 8388608);    //  6291456 B
  uint16_t* WprojT = (uint16_t*)(wsb + 25165824 + 8388608 + 6291456);

  dim3 blk(256);

  cvt_bf16<<<dim3((BB * LL * DM / 4 + 255) / 256), blk, 0, stream>>>(hs, hsctxb, BB * LL * DM / 4);
  transpose_cvt<<<dim3(3 * DM / 32, DM / 32), blk, 0, stream>>>(Wqkv, WqkvT, DM, 3 * DM);
  transpose_cvt<<<dim3(DM / 32, DM / 32), blk, 0, stream>>>(Wproj, WprojT, DM, DM);

  gemm_bt<1><<<dim3(3 * DM / 128, BB * LL / 128), blk, 0, stream>>>(
      hsctxb, WqkvT, bqkv, (void*)qkv, BB * LL, 3 * DM, DM);

  attn_sw<<<dim3(BB * NH * (LL / QT)), blk, 0, stream>>>(qkv, attnw, hsctxb, wszp);

  gemm_bt<0><<<dim3(DM / 128, BB * LL / 128), blk, 0, stream>>>(
      hsctxb, WprojT, bproj, (void*)out, BB * LL, DM, DM);
}

// Round 2
// 652.428 us; speedup vs baseline: 1.0076x; 1.0076x over previous
//
#include <hip/hip_runtime.h>
#include <stdint.h>

#define NH 16
#define HD 64
#define DM 1024
#define BB 2
#define LL 2048

typedef __bf16 bf16x8 __attribute__((ext_vector_type(8)));
typedef float f32x4 __attribute__((ext_vector_type(4)));
typedef unsigned short u16x8 __attribute__((ext_vector_type(8)));

__device__ __forceinline__ uint16_t f2bf(float f) {
  union { float f; uint32_t u; } x{f};
  uint32_t r = (x.u + 0x7fff + ((x.u >> 16) & 1)) >> 16;
  return (uint16_t)r;
}

__device__ __forceinline__ void gload_lds16(const void* g, void* l) {
  __builtin_amdgcn_global_load_lds(
      (const __attribute__((address_space(1))) unsigned int*)g,
      (__attribute__((address_space(3))) unsigned int*)l, 16, 0, 0);
}

// ---------------- fused prep: fp32->bf16 cast of hs + two weight transposes
// blocks [0, 4096)        : cvt hs -> hsb           (4096*256 float4 = 4M)
// blocks [4096, 7168)     : Wqkv [1024,3072] -> WqkvT [3072,1024]  (96x32 tiles)
// blocks [7168, 8192)     : Wproj [1024,1024] -> WprojT [1024,1024] (32x32 tiles)
__device__ __forceinline__ void transpose_tile(
    const float* __restrict__ W, uint16_t* __restrict__ WT, int K, int N,
    int bk, int bn, float (*t)[33]) {
  int c = threadIdx.x & 31, r0 = threadIdx.x >> 5;
#pragma unroll
  for (int p = 0; p < 4; ++p) {
    int r = r0 + p * 8;
    t[r][c] = W[(size_t)(bk + r) * N + bn + c];
  }
  __syncthreads();
#pragma unroll
  for (int p = 0; p < 4; ++p) {
    int r = r0 + p * 8;
    WT[(size_t)(bn + r) * K + bk + c] = f2bf(t[c][r]);
  }
}

__global__ __launch_bounds__(256) void prep(
    const float* __restrict__ hs, uint16_t* __restrict__ hsb,
    const float* __restrict__ Wqkv, uint16_t* __restrict__ WqkvT,
    const float* __restrict__ Wproj, uint16_t* __restrict__ WprojT) {
  __shared__ float t[32][33];
  int bid = blockIdx.x;
  if (bid < 4096) {
    int i = bid * 256 + threadIdx.x;  // n4 = 4194304/4 = 1048576 -> 4096 blocks
    float4 v = ((const float4*)hs)[i];
    ushort4 o;
    o.x = f2bf(v.x); o.y = f2bf(v.y); o.z = f2bf(v.z); o.w = f2bf(v.w);
    ((ushort4*)hsb)[i] = o;
  } else if (bid < 7168) {
    int id = bid - 4096;                       // (96 x 32) tiles, N=3072 K=1024
    int bx = id % 96, by = id / 96;
    transpose_tile(Wqkv, WqkvT, DM, 3 * DM, by * 32, bx * 32, t);
  } else {
    int id = bid - 7168;                       // (32 x 32) tiles, N=1024 K=1024
    int bx = id % 32, by = id / 32;
    transpose_tile(Wproj, WprojT, DM, DM, by * 32, bx * 32, t);
  }
}

// ---------------- bf16 MFMA GEMM: C[M,N] = A @ BT^T + bias
// Swapped-operand mfma(bfr, af): lane&15 = C-row, (lane>>4)*4+reg = C-col
// -> vectorized epilogue (float4 / ushort4 per lane).
// 1D grid + bijective XCD swizzle (nwg % 8 == 0 for both call sites).
// OBF=1: C is bf16 (uint16_t*), OBF=0: C is fp32 (float*).
template <int OBF>
__global__ __launch_bounds__(256) void gemm_bt(
    const uint16_t* __restrict__ A, const uint16_t* __restrict__ BT,
    const float* __restrict__ bias, void* __restrict__ Cout,
    int M, int N, int K) {
  __shared__ uint16_t As[128 * 32];
  __shared__ uint16_t Bs[128 * 32];
  const int tid = threadIdx.x;
  const int nwg = gridDim.x;
  int wg = blockIdx.x;
  wg = (wg & 7) * (nwg >> 3) + (wg >> 3);   // XCD-contiguous chunks
  const int gx = N >> 7;
  const int bm = (wg / gx) * 128, bn = (wg % gx) * 128;
  const int lane = tid & 63, wave = tid >> 6;
  const int wr = wave >> 1, wc = wave & 1;
  f32x4 acc[4][4] = {};

  for (int k0 = 0; k0 < K; k0 += 32) {
#pragma unroll
    for (int c = 0; c < 2; ++c) {
      int e = c * 2048 + tid * 8;
      int r = e >> 5, col = e & 31;
      gload_lds16(A + (size_t)(bm + r) * K + k0 + col, (char*)As + (size_t)e * 2);
      gload_lds16(BT + (size_t)(bn + r) * K + k0 + col, (char*)Bs + (size_t)e * 2);
    }
    __syncthreads();

    const int kseg = (lane >> 4) * 8;
    bf16x8 af[4], bfr[4];
#pragma unroll
    for (int i = 0; i < 4; ++i)
      af[i] = *(const bf16x8*)&As[(wr * 64 + i * 16 + (lane & 15)) * 32 + kseg];
#pragma unroll
    for (int j = 0; j < 4; ++j)
      bfr[j] = *(const bf16x8*)&Bs[(wc * 64 + j * 16 + (lane & 15)) * 32 + kseg];
#pragma unroll
    for (int i = 0; i < 4; ++i)
#pragma unroll
      for (int j = 0; j < 4; ++j)
        acc[i][j] = __builtin_amdgcn_mfma_f32_16x16x32_bf16(bfr[j], af[i], acc[i][j], 0, 0, 0);
    __syncthreads();
  }

#pragma unroll
  for (int i = 0; i < 4; ++i) {
#pragma unroll
    for (int j = 0; j < 4; ++j) {
      int row = bm + wr * 64 + i * 16 + (lane & 15);
      int col = bn + wc * 64 + j * 16 + (lane >> 4) * 4;
      f32x4 bv = *(const f32x4*)&bias[col];
      f32x4 v = acc[i][j] + bv;
      if (OBF) {
        ushort4 o;
        o.x = f2bf(v[0]); o.y = f2bf(v[1]); o.z = f2bf(v[2]); o.w = f2bf(v[3]);
        *(ushort4*)&((uint16_t*)Cout)[(size_t)row * N + col] = o;
      } else {
        *(f32x4*)&((float*)Cout)[(size_t)row * N + col] = v;
      }
    }
  }
}

// ---------------- MFMA sliding-window attention (bf16 qkv input)
// Per block: 32 q-rows, 160-key window (kbase 32-aligned). 4 waves.
// S = Q K^T via mfma 16x16x32 (bf16), softmax fp32, P -> LDS bf16,
// O = P V via mfma with V gathered from global as B-fragment.
#define QT 32
#define KT 160
#define KS 72    // Ks/Qs row stride (bf16): 144 B, 16B-aligned
#define PS 168   // Sf/Psb row stride: Sf 672 B, Psb 336 B

__global__ __launch_bounds__(256, 4) void attn_sw(
    const uint16_t* __restrict__ qkv,  // [B*L, 3*DM] bf16
    float* __restrict__ attnw,         // [B,NH,L,L] - fully written here
    uint16_t* __restrict__ ctxb,       // [B*L, DM] bf16
    const int* __restrict__ wsz_p) {
  __shared__ __align__(16) char smemU[KT * KS * 2];     // Ksb (bf16) / Sf (f32)
  __shared__ __align__(16) uint16_t Qs[QT * KS];
  __shared__ __align__(16) uint16_t Psb[QT * PS];
  uint16_t* Ksb = (uint16_t*)smemU;   // [160][72] bf16
  float* Sf = (float*)smemU;          // [32][168] f32 (after K no longer needed)

  const int wsz = *wsz_p;  // 128
  const int tid = threadIdx.x;
  const int lane = tid & 63, wave = tid >> 6;
  const int ntile = LL / QT;
  const int qt = blockIdx.x % ntile;
  const int h = (blockIdx.x / ntile) % NH;
  const int b = blockIdx.x / (ntile * NH);
  const int q0 = qt * QT;
  const int kmin = max(0, q0 - (wsz - 1));
  const int kbase = kmin & ~31;  // 32-aligned; window rows always in-tensor

  // ---- P0: stage Q (32x64) and K (160x64), pure 16B bf16 copies
  {
    int r = tid >> 3, c = (tid & 7) * 8;
    *(u16x8*)&Qs[r * KS + c] =
        *(const u16x8*)(qkv + (size_t)(b * LL + q0 + r) * (3 * DM) + h * HD + c);
  }
#pragma unroll
  for (int p = 0; p < 5; ++p) {  // 160 rows * 8 chunks = 1280 = 5*256
    int u = tid + p * 256;
    int r = u >> 3, c = (u & 7) * 8;
    *(u16x8*)&Ksb[r * KS + c] =
        *(const u16x8*)(qkv + (size_t)(b * LL + kbase + r) * (3 * DM) + DM + h * HD + c);
  }
  __syncthreads();

  // ---- P1a: S-fragments in registers. wave w: m-tile (w&1), n-tiles [(w>>1)*5 ..+5)
  const int mt = wave & 1, ntb = (wave >> 1) * 5;
  f32x4 sfrag[5];
  {
    const int kseg = (lane >> 4) * 8;
    bf16x8 aq0 = *(const bf16x8*)&Qs[(mt * 16 + (lane & 15)) * KS + kseg];
    bf16x8 aq1 = *(const bf16x8*)&Qs[(mt * 16 + (lane & 15)) * KS + 32 + kseg];
#pragma unroll
    for (int t = 0; t < 5; ++t) {
      int nt = ntb + t;
      bf16x8 bk0 = *(const bf16x8*)&Ksb[(nt * 16 + (lane & 15)) * KS + kseg];
      bf16x8 bk1 = *(const bf16x8*)&Ksb[(nt * 16 + (lane & 15)) * KS + 32 + kseg];
      f32x4 c = {0.f, 0.f, 0.f, 0.f};
      c = __builtin_amdgcn_mfma_f32_16x16x32_bf16(aq0, bk0, c, 0, 0, 0);
      c = __builtin_amdgcn_mfma_f32_16x16x32_bf16(aq1, bk1, c, 0, 0, 0);
      sfrag[t] = c;
    }
  }
  __syncthreads();  // Ksb reads done; Sf may now overwrite the union

  // ---- P1b: spill S-fragments to Sf (fp32)
#pragma unroll
  for (int t = 0; t < 5; ++t) {
    int nt = ntb + t;
#pragma unroll
    for (int r = 0; r < 4; ++r)
      Sf[(mt * 16 + (lane >> 4) * 4 + r) * PS + nt * 16 + (lane & 15)] = sfrag[t][r];
  }
  __syncthreads();

  // ---- P2: softmax (octet per q-row), probs -> Sf (f32) and Psb (bf16)
  {
    const int qi = tid >> 3;
    const int kg = tid & 7;
    const int q = q0 + qi;
    float s[20];
#pragma unroll
    for (int j = 0; j < 20; ++j) s[j] = Sf[qi * PS + kg + 8 * j];
    float m = -1e30f;
#pragma unroll
    for (int j = 0; j < 20; ++j) {
      int gk = kbase + kg + 8 * j;
      bool valid = (gk <= q) && (gk > q - wsz);
      s[j] = valid ? s[j] * 0.125f : -1e30f;
      m = fmaxf(m, s[j]);
    }
#pragma unroll
    for (int off = 1; off < 8; off <<= 1)
      m = fmaxf(m, __shfl_xor(m, off, 64));
    float l = 0.f;
#pragma unroll
    for (int j = 0; j < 20; ++j) {
      float e = (s[j] > -1e29f) ? __expf(s[j] - m) : 0.f;
      s[j] = e;
      l += e;
    }
#pragma unroll
    for (int off = 1; off < 8; off <<= 1)
      l += __shfl_xor(l, off, 64);
    float inv = 1.f / l;
#pragma unroll
    for (int j = 0; j < 20; ++j) {
      float p = s[j] * inv;
      Sf[qi * PS + kg + 8 * j] = p;
      Psb[qi * PS + kg + 8 * j] = f2bf(p);
    }
  }
  __syncthreads();

  // ---- P3: full attnw rows (zeros + band) from Sf, nt float4 stores.
  // Issued before PV so the HBM write stream overlaps the MFMA work.
  {
#pragma unroll
    for (int it = 0; it < 16; ++it) {
      int r = it * 2 + (tid >> 7);
      size_t rowoff = ((size_t)((b * NH + h) * LL + q0 + r)) * LL;
      int cb = (tid & 127) * 4;
#pragma unroll
      for (int jj = 0; jj < 4; ++jj) {
        int c4 = cb + jj * 512;
        f32x4 v = {0.f, 0.f, 0.f, 0.f};
        int pc = c4 - kbase;
        if (pc >= 0 && pc < KT)
          v = *(const f32x4*)&Sf[r * PS + pc];
        __builtin_nontemporal_store(v, (f32x4*)&attnw[rowoff + c4]);
      }
    }
  }

  // ---- P4: O = P V via MFMA. wave w: n-tile (d-cols) = w; both m-tiles.
  {
    const int nt = wave;           // d block: nt*16 + (lane&15)
    const int kseg = (lane >> 4) * 8;
    f32x4 ofrag[2] = {};
#pragma unroll
    for (int ks = 0; ks < 5; ++ks) {
      // B-fragment: V^T[d][key], gathered from global (bf16, 2B loads)
      const uint16_t* vs = qkv + (size_t)(b * LL + kbase + ks * 32 + kseg) * (3 * DM) +
                           2 * DM + h * HD + nt * 16 + (lane & 15);
      uint16_t vb[8];
#pragma unroll
      for (int j = 0; j < 8; ++j) vb[j] = vs[(size_t)j * (3 * DM)];
      bf16x8 bv = *(const bf16x8*)vb;
#pragma unroll
      for (int m = 0; m < 2; ++m) {
        bf16x8 ap = *(const bf16x8*)&Psb[(m * 16 + (lane & 15)) * PS + ks * 32 + kseg];
        ofrag[m] = __builtin_amdgcn_mfma_f32_16x16x32_bf16(ap, bv, ofrag[m], 0, 0, 0);
      }
    }
#pragma unroll
    for (int m = 0; m < 2; ++m)
#pragma unroll
      for (int r = 0; r < 4; ++r) {
        int q = q0 + m * 16 + (lane >> 4) * 4 + r;
        ctxb[(size_t)(b * LL + q) * DM + h * HD + nt * 16 + (lane & 15)] = f2bf(ofrag[m][r]);
      }
  }
}

extern "C" void kernel_launch(void* const* d_in, const int* in_sizes, int n_in,
                              void* d_out, int out_size, void* d_ws, size_t ws_size,
                              hipStream_t stream) {
  const float* hs    = (const float*)d_in[0];
  const float* Wqkv  = (const float*)d_in[1];
  const float* bqkv  = (const float*)d_in[2];
  const float* Wproj = (const float*)d_in[3];
  const float* bproj = (const float*)d_in[4];
  const int*   wszp  = (const int*)d_in[5];

  float* out   = (float*)d_out;
  float* attnw = (float*)d_out + (size_t)BB * LL * DM;

  char* wsb = (char*)d_ws;
  uint16_t* qkv    = (uint16_t*)wsb;                           // 25165824 B (bf16)
  uint16_t* hsctxb = (uint16_t*)(wsb + 25165824);              //  8388608 B
  uint16_t* WqkvT  = (uint16_t*)(wsb + 25165824 + 8388608);    //  6291456 B
  uint16_t* WprojT = (uint16_t*)(wsb + 25165824 + 8388608 + 6291456);

  dim3 blk(256);

  prep<<<dim3(8192), blk, 0, stream>>>(hs, hsctxb, Wqkv, WqkvT, Wproj, WprojT);

  gemm_bt<1><<<dim3(768), blk, 0, stream>>>(
      hsctxb, WqkvT, bqkv, (void*)qkv, BB * LL, 3 * DM, DM);

  attn_sw<<<dim3(BB * NH * (LL / QT)), blk, 0, stream>>>(qkv, attnw, hsctxb, wszp);

  gemm_bt<0><<<dim3(256), blk, 0, stream>>>(
      hsctxb, WprojT, bproj, (void*)out, BB * LL, DM, DM);
}